// Round 1
// baseline (310.404 us; speedup 1.0000x reference)
//
#include <hip/hip_runtime.h>
#include <math.h>

// ToneStack: 3 cascaded shelf biquads over x[64, 480000] fp32.
// Parallel-over-time via chunked IIR with truncated warm-up:
//   slowest pole r=0.99069 (120Hz shelf) -> zero-input response after
//   W=1536 samples is ~2e-4 relative, vs absmax threshold 0.12.
// Each thread owns one (row, chunk): runs W warm-up samples (no stores),
// then L=480 output samples. 64000 threads = 1000 waves (~1/SIMD).

constexpr int T_LEN  = 480000;
constexpr int B_ROWS = 64;
constexpr int CHUNK  = 480;            // L: output samples per thread
constexpr int WARM   = 1536;           // W: warm-up samples (multiple of 32)
constexpr int KCH    = T_LEN / CHUNK;  // 1000 chunks per row
constexpr int NTHR   = B_ROWS * KCH;   // 64000 threads

struct Coeffs { float b0, b1, b2, a1, a2; };

__device__ __forceinline__ Coeffs shelf(float fc, float gdb, float Q) {
    float A  = powf(10.0f, gdb * (1.0f / 40.0f));
    float w0 = 2.0f * 3.14159265358979323846f * fc / 48000.0f;
    float sw = sinf(w0), cw = cosf(w0);
    float alpha = sw / (2.0f * Q);
    float sqA = sqrtf(A);
    float b0 = A * ((A + 1.0f) - (A - 1.0f) * cw + 2.0f * sqA * alpha);
    float b1 = 2.0f * A * ((A - 1.0f) - (A + 1.0f) * cw);
    float b2 = A * ((A + 1.0f) - (A - 1.0f) * cw - 2.0f * sqA * alpha);
    float a0 = (A + 1.0f) + (A - 1.0f) * cw + 2.0f * sqA * alpha;
    float a1 = -2.0f * ((A - 1.0f) + (A + 1.0f) * cw);
    float a2 = (A + 1.0f) + (A - 1.0f) * cw - 2.0f * sqA * alpha;
    float rr = 1.0f / a0;
    Coeffs c;
    c.b0 = b0 * rr; c.b1 = b1 * rr; c.b2 = b2 * rr;
    c.a1 = a1 * rr; c.a2 = a2 * rr;
    return c;
}

// Direct-form-II-transposed biquad step (matches reference exactly):
//   y  = b0*x + z1
//   z1 = b1*x - a1*y + z2
//   z2 = b2*x - a2*y
__device__ __forceinline__ float bq(float xn, const Coeffs& c, float& z1, float& z2) {
    float y = fmaf(c.b0, xn, z1);
    z1 = fmaf(-c.a1, y, fmaf(c.b1, xn, z2));
    z2 = fmaf(c.b2, xn, -(c.a2 * y));
    return y;
}

__global__ __launch_bounds__(256) void tonestack_kernel(
    const float* __restrict__ x,
    const float* __restrict__ p_lg, const float* __restrict__ p_mg,
    const float* __restrict__ p_mf, const float* __restrict__ p_mq,
    const float* __restrict__ p_hg,
    float* __restrict__ out)
{
    int tid = blockIdx.x * blockDim.x + threadIdx.x;
    if (tid >= NTHR) return;
    int r = tid / KCH;
    int k = tid - r * KCH;

    Coeffs c1 = shelf(120.0f,  *p_lg, 0.707f);
    Coeffs c2 = shelf(*p_mf,   *p_mg, *p_mq);
    Coeffs c3 = shelf(4000.0f, *p_hg, 0.707f);

    const float* xr = x   + (long long)r * T_LEN;
    float*       yr = out + (long long)r * T_LEN;

    int start = k * CHUNK;
    int warm  = min(start, WARM);   // chunks 0..3 get exact (shorter) history
    int p0    = start - warm;       // multiple of 32 -> 16B-aligned float4s
    int nblk  = (warm + CHUNK) >> 5;

    float z11 = 0.f, z12 = 0.f, z21 = 0.f, z22 = 0.f, z31 = 0.f, z32 = 0.f;

    // 32-sample register line buffer, prefetched one block ahead so the
    // global load latency (~200-900 cyc) is hidden behind ~1100 cyc of FMAs.
    float4 nxt[8];
    {
        const float4* lp = (const float4*)(xr + p0);
        #pragma unroll
        for (int j = 0; j < 8; ++j) nxt[j] = lp[j];
    }

    int pos = p0;
    #pragma unroll 1
    for (int blk = 0; blk < nblk; ++blk, pos += 32) {
        float4 cur[8];
        #pragma unroll
        for (int j = 0; j < 8; ++j) cur[j] = nxt[j];

        if (blk + 1 < nblk) {
            const float4* lp = (const float4*)(xr + pos + 32);
            #pragma unroll
            for (int j = 0; j < 8; ++j) nxt[j] = lp[j];
        }

        const bool wr = (pos >= start);   // block boundaries align with start
        float4* sp = (float4*)(yr + pos);
        #pragma unroll
        for (int j = 0; j < 8; ++j) {
            float4 v = cur[j];
            float4 o;
            o.x = bq(bq(bq(v.x, c1, z11, z12), c2, z21, z22), c3, z31, z32);
            o.y = bq(bq(bq(v.y, c1, z11, z12), c2, z21, z22), c3, z31, z32);
            o.z = bq(bq(bq(v.z, c1, z11, z12), c2, z21, z22), c3, z31, z32);
            o.w = bq(bq(bq(v.w, c1, z11, z12), c2, z21, z22), c3, z31, z32);
            if (wr) sp[j] = o;
        }
    }
}

extern "C" void kernel_launch(void* const* d_in, const int* in_sizes, int n_in,
                              void* d_out, int out_size, void* d_ws, size_t ws_size,
                              hipStream_t stream) {
    const float* x  = (const float*)d_in[0];
    const float* lg = (const float*)d_in[1];
    const float* mg = (const float*)d_in[2];
    const float* mf = (const float*)d_in[3];
    const float* mq = (const float*)d_in[4];
    const float* hg = (const float*)d_in[5];
    float* out = (float*)d_out;

    dim3 grid(NTHR / 256);
    dim3 block(256);
    hipLaunchKernelGGL(tonestack_kernel, grid, block, 0, stream,
                       x, lg, mg, mf, mq, hg, out);
}